// Round 9
// baseline (632.316 us; speedup 1.0000x reference)
//
#include <hip/hip_runtime.h>
#include <hip/hip_bf16.h>
#include <hip/hip_cooperative_groups.h>

namespace cg = cooperative_groups;

constexpr int N_NODES = 40000;
constexpr int N_EDGES = 640000;
constexpr int D = 128;
constexpr float BN_EPS = 1e-5f;
constexpr int SCAN_BLOCKS = 157;   // ceil(40000/256)
constexpr int GRID = 512;          // 2 blocks/CU co-resident
constexpr int NTHREADS = GRID * 256;

typedef __attribute__((ext_vector_type(8))) short short8;
typedef __attribute__((ext_vector_type(4))) float f32x4;

static_assert(N_EDGES == N_NODES * D / 8, "phase-1 fusion assumes equal ranges");

__device__ __forceinline__ unsigned bf16_rne(float f) {
    unsigned b = __float_as_uint(f);
    return (b + 0x7FFFu + ((b >> 16) & 1u)) >> 16;
}
__device__ __forceinline__ float bflo(unsigned w) { return __uint_as_float(w << 16); }
__device__ __forceinline__ float bfhi(unsigned w) { return __uint_as_float(w & 0xFFFF0000u); }

// ---------------------------------------------------------------------------
// One cooperative mega-kernel: all phases, grid.sync() between them.
// Eliminates 8 dispatch launch/tail gaps and gives single-dispatch counters.
// ---------------------------------------------------------------------------
__global__ __launch_bounds__(256) void mega_kernel(
        const int* __restrict__ dst,
        const int* __restrict__ src,
        const float4* __restrict__ h4,
        const float* __restrict__ snorm,
        const float* __restrict__ Wself,
        const float* __restrict__ Wneigh,
        const float* __restrict__ bias,
        const float4* __restrict__ gamma4,
        const float4* __restrict__ beta4,
        float* __restrict__ out,
        int* __restrict__ deg_i,
        int* __restrict__ cursor,
        float* __restrict__ sums,
        float* __restrict__ sumsq,
        int* __restrict__ row_start,
        int* __restrict__ partials,
        int* __restrict__ esrc,
        uint4* __restrict__ wfrag,
        uint4* __restrict__ hb4,
        uint4* __restrict__ hnb4) {
    cg::grid_group grid = cg::this_grid();
    __shared__ uint4 ldsW[2048];     // 32 KB (gemm W half)
    __shared__ int sh[256];          // scan scratch
    __shared__ int offs_sh;
    __shared__ float sums_l[D];
    __shared__ float sumsq_l[D];

    const int t = threadIdx.x;
    const int b = blockIdx.x;
    const int gtid = b * 256 + t;

    // ---- P0: zero accumulators (deg_i & cursor are contiguous in ws) ----
    for (int i = gtid; i < 2 * N_NODES; i += NTHREADS) deg_i[i] = 0;
    if (gtid < 2 * D) sums[gtid] = 0.f;   // sums & sumsq contiguous
    grid.sync();

    // ---- P1: degree histogram + h->bf16 + W->frag-major bf16 ----
    for (int e = gtid; e < N_EDGES; e += NTHREADS) {
        atomicAdd(&deg_i[dst[e]], 1);
        float4 a = h4[2 * e];
        float4 bb = h4[2 * e + 1];
        uint4 o;
        o.x = bf16_rne(a.x) | (bf16_rne(a.y) << 16);
        o.y = bf16_rne(a.z) | (bf16_rne(a.w) << 16);
        o.z = bf16_rne(bb.x) | (bf16_rne(bb.y) << 16);
        o.w = bf16_rne(bb.z) | (bf16_rne(bb.w) << 16);
        hb4[e] = o;
    }
    // W frag layout: granule G=(ct*8+kt)*64 + kg*16 + n holds j=0..7 of
    // Wcat[k=kt*32+kg*8+j][col=ct*16+n], Wcat=[Wself;Wneigh].
    if (gtid < 4096) {
        int G = gtid;
        int l = G & 63;
        int tile = G >> 6;
        int kg = l >> 4, n = l & 15;
        int ct = tile >> 3, kt = tile & 7;
        int k0 = kt * 32 + kg * 8;
        int col = ct * 16 + n;
        unsigned w[8];
        #pragma unroll
        for (int j = 0; j < 8; j++) {
            int k = k0 + j;
            float v = (k < D) ? Wself[(size_t)k * D + col]
                              : Wneigh[(size_t)(k - D) * D + col];
            w[j] = bf16_rne(v);
        }
        uint4 ow;
        ow.x = w[0] | (w[1] << 16);
        ow.y = w[2] | (w[3] << 16);
        ow.z = w[4] | (w[5] << 16);
        ow.w = w[6] | (w[7] << 16);
        wfrag[G] = ow;
    }
    grid.sync();

    // ---- P2: scan phase 1 (per-block partial sums) ----
    if (b < SCAN_BLOCKS) {
        int i = b * 256 + t;
        sh[t] = (i < N_NODES) ? deg_i[i] : 0;
        __syncthreads();
        for (int off = 128; off >= 1; off >>= 1) {
            if (t < off) sh[t] += sh[t + off];
            __syncthreads();
        }
        if (t == 0) partials[b] = sh[0];
    }
    grid.sync();

    // ---- P3: scan phases 2+3 -> row_start ----
    if (b < SCAN_BLOCKS) {
        sh[t] = (t < b) ? partials[t] : 0;
        __syncthreads();
        for (int off = 128; off >= 1; off >>= 1) {
            if (t < off) sh[t] += sh[t + off];
            __syncthreads();
        }
        if (t == 0) offs_sh = sh[0];
        __syncthreads();
        int offs = offs_sh;
        int i = b * 256 + t;
        int v = (i < N_NODES) ? deg_i[i] : 0;
        __syncthreads();
        sh[t] = v;
        __syncthreads();
        for (int off = 1; off < 256; off <<= 1) {
            int u = (t >= off) ? sh[t - off] : 0;
            __syncthreads();
            sh[t] += u;
            __syncthreads();
        }
        if (i < N_NODES) row_start[i] = sh[t] - v + offs;
        if (b == SCAN_BLOCKS - 1 && t == 255) row_start[N_NODES] = sh[255] + offs;
    }
    grid.sync();

    // ---- P4: bucket fill ----
    for (int e = gtid; e < N_EDGES; e += NTHREADS) {
        int tt = dst[e];
        int p = atomicAdd(&cursor[tt], 1);
        esrc[row_start[tt] + p] = src[e];
    }
    grid.sync();

    // ---- P5: gather + mean (one wave per node, grid-strided) ----
    {
        int lane = t & 63;
        int g = lane & 15;
        int es = lane >> 4;
        int wglob = b * 4 + (t >> 6);
        for (int node = wglob; node < N_NODES; node += GRID * 4) {
            int s0 = row_start[node];
            int s1 = row_start[node + 1];
            float acc[8] = {0.f, 0.f, 0.f, 0.f, 0.f, 0.f, 0.f, 0.f};
            for (int j = s0 + es; j < s1; j += 4) {
                int a = esrc[j];
                uint4 v = hb4[(size_t)a * 16 + g];
                acc[0] += bflo(v.x); acc[1] += bfhi(v.x);
                acc[2] += bflo(v.y); acc[3] += bfhi(v.y);
                acc[4] += bflo(v.z); acc[5] += bfhi(v.z);
                acc[6] += bflo(v.w); acc[7] += bfhi(v.w);
            }
            #pragma unroll
            for (int i = 0; i < 8; i++) {
                acc[i] += __shfl_xor(acc[i], 16);
                acc[i] += __shfl_xor(acc[i], 32);
            }
            if (es == 0) {
                int len = s1 - s0;
                float rd = 1.0f / (float)(len > 1 ? len : 1);
                uint4 o;
                o.x = bf16_rne(acc[0] * rd) | (bf16_rne(acc[1] * rd) << 16);
                o.y = bf16_rne(acc[2] * rd) | (bf16_rne(acc[3] * rd) << 16);
                o.z = bf16_rne(acc[4] * rd) | (bf16_rne(acc[5] * rd) << 16);
                o.w = bf16_rne(acc[6] * rd) | (bf16_rne(acc[7] * rd) << 16);
                hnb4[(size_t)node * 16 + g] = o;
            }
        }
    }
    grid.sync();

    // ---- P6: MFMA dual GEMM (tile = 64 rows x 64-col half), grid-strided.
    // Tiles ordered col-half-major so each block restages LDS W at most once.
    {
        if (t < D) { sums_l[t] = 0.f; sumsq_l[t] = 0.f; }
        int lane = t & 63;
        int wid = t >> 6;
        int n = lane & 15;
        int kg = lane >> 4;
        int cur_cbt = -1;
        for (int idx = b; idx < 1250; idx += GRID) {
            int cbt = (idx >= 625) ? 1 : 0;
            int rowtile = idx - cbt * 625;
            if (cbt != cur_cbt) {
                __syncthreads();
                #pragma unroll
                for (int i = 0; i < 8; i++) {
                    int g = i * 256 + t;
                    ldsW[g] = wfrag[cbt * 2048 + g];
                }
                __syncthreads();
                cur_cbt = cbt;
            }
            int cb = cbt * 64;
            int row_base = rowtile * 64 + wid * 16;
            int row = row_base + n;

            short8 a[8];
            #pragma unroll
            for (int kt = 0; kt < 4; kt++) {
                uint4 v = hb4[(size_t)row * 16 + kt * 4 + kg];
                a[kt] = __builtin_bit_cast(short8, v);
            }
            #pragma unroll
            for (int kt = 0; kt < 4; kt++) {
                uint4 v = hnb4[(size_t)row * 16 + kt * 4 + kg];
                a[4 + kt] = __builtin_bit_cast(short8, v);
            }

            f32x4 acc[4];
            #pragma unroll
            for (int lt = 0; lt < 4; lt++) acc[lt] = (f32x4){0.f, 0.f, 0.f, 0.f};
            #pragma unroll
            for (int lt = 0; lt < 4; lt++) {
                #pragma unroll
                for (int kt = 0; kt < 8; kt++) {
                    short8 bb = __builtin_bit_cast(short8, ldsW[(lt * 8 + kt) * 64 + lane]);
                    acc[lt] = __builtin_amdgcn_mfma_f32_16x16x32_bf16(a[kt], bb, acc[lt], 0, 0, 0);
                }
            }

            float snv[4];
            #pragma unroll
            for (int r = 0; r < 4; r++) snv[r] = snorm[row_base + kg * 4 + r];

            #pragma unroll
            for (int lt = 0; lt < 4; lt++) {
                int col = cb + lt * 16 + n;
                float bbias = bias[col];
                float csum = 0.f, csq = 0.f;
                #pragma unroll
                for (int r = 0; r < 4; r++) {
                    int rr = row_base + kg * 4 + r;
                    float v = acc[lt][r] + bbias;
                    v = fmaxf(v, 0.f);
                    v *= snv[r];
                    out[(size_t)rr * D + col] = v;     // pre, f32, in d_out
                    csum += v;
                    csq += v * v;
                }
                csum += __shfl_xor(csum, 16); csq += __shfl_xor(csq, 16);
                csum += __shfl_xor(csum, 32); csq += __shfl_xor(csq, 32);
                if (kg == 0) {
                    atomicAdd(&sums_l[col], csum);
                    atomicAdd(&sumsq_l[col], csq);
                }
            }
        }
        __syncthreads();
        if (t < D) {
            atomicAdd(&sums[t], sums_l[t]);
            atomicAdd(&sumsq[t], sumsq_l[t]);
        }
    }
    grid.sync();

    // ---- P7: finalize in place: out = h + (pre - mean)*scale + beta ----
    {
        const float invN = 1.0f / (float)N_NODES;
        const float4* sums4 = (const float4*)sums;
        const float4* sumsq4 = (const float4*)sumsq;
        float4* out4 = (float4*)out;
        for (int idx = gtid; idx < N_NODES * D / 4; idx += NTHREADS) {
            int d4 = idx & 31;
            float4 s = sums4[d4];
            float4 sq = sumsq4[d4];
            float4 g = gamma4[d4];
            float4 bt = beta4[d4];
            float4 hv = h4[idx];
            float4 ov = out4[idx];
            float m, var, sc;
            m = s.x * invN; var = sq.x * invN - m * m; sc = g.x * rsqrtf(var + BN_EPS);
            ov.x = hv.x + (ov.x - m) * sc + bt.x;
            m = s.y * invN; var = sq.y * invN - m * m; sc = g.y * rsqrtf(var + BN_EPS);
            ov.y = hv.y + (ov.y - m) * sc + bt.y;
            m = s.z * invN; var = sq.z * invN - m * m; sc = g.z * rsqrtf(var + BN_EPS);
            ov.z = hv.z + (ov.z - m) * sc + bt.z;
            m = s.w * invN; var = sq.w * invN - m * m; sc = g.w * rsqrtf(var + BN_EPS);
            ov.w = hv.w + (ov.w - m) * sc + bt.w;
            out4[idx] = ov;
        }
    }
}

// ---------------------------------------------------------------------------
extern "C" void kernel_launch(void* const* d_in, const int* in_sizes, int n_in,
                              void* d_out, int out_size, void* d_ws, size_t ws_size,
                              hipStream_t stream) {
    const float4* h4    = (const float4*)d_in[0];
    const float*  snorm = (const float*)d_in[1];
    const float*  Wself = (const float*)d_in[2];
    const float*  Wneigh= (const float*)d_in[3];
    const float*  bias  = (const float*)d_in[4];
    const float4* gamma4= (const float4*)d_in[5];
    const float4* beta4 = (const float4*)d_in[6];
    const int*    src   = (const int*)d_in[7];
    const int*    dst   = (const int*)d_in[8];
    float* out = (float*)d_out;

    // ws layout:
    // [ deg_i : N ][ cursor : N ][ sums : D f ][ sumsq : D f ]
    // [ row_start : N+1 ][ partials : 160 ][ esrc : E ]
    // [ wfrag : 64KB ][ hb : 10.2MB ][ hnb : 10.2MB ]
    int*   deg_i     = (int*)d_ws;
    int*   cursor    = deg_i + N_NODES;
    float* sums      = (float*)(cursor + N_NODES);
    float* sumsq     = sums + D;
    int*   row_start = (int*)(sumsq + D);
    int*   partials  = row_start + (N_NODES + 1);
    int*   esrc      = partials + 160;
    size_t off       = (size_t)((char*)(esrc + N_EDGES) - (char*)d_ws);
    off = (off + 15) & ~(size_t)15;
    uint4* wfrag = (uint4*)((char*)d_ws + off);
    uint4* hb4   = wfrag + 4096;
    uint4* hnb4  = hb4 + N_NODES * (D / 8);

    void* args[] = {
        (void*)&dst, (void*)&src, (void*)&h4, (void*)&snorm, (void*)&Wself,
        (void*)&Wneigh, (void*)&bias, (void*)&gamma4, (void*)&beta4,
        (void*)&out, (void*)&deg_i, (void*)&cursor, (void*)&sums,
        (void*)&sumsq, (void*)&row_start, (void*)&partials, (void*)&esrc,
        (void*)&wfrag, (void*)&hb4, (void*)&hnb4,
    };
    hipLaunchCooperativeKernel((const void*)mega_kernel, dim3(GRID), dim3(256),
                               args, 0, stream);
}